// Round 3
// baseline (2724.784 us; speedup 1.0000x reference)
//
#include <hip/hip_runtime.h>

#define BATCH    1048576
#define IN_DIM   16
#define ODE_DIM  64
#define OUT_DIM  16
#define N_STEPS  32

typedef _Float16 half2v __attribute__((ext_vector_type(2)));
typedef _Float16 half4v __attribute__((ext_vector_type(4)));
typedef _Float16 half8v __attribute__((ext_vector_type(8)));
typedef float    f32x16 __attribute__((ext_vector_type(16)));

// 64 dims + 4 pad halfs per row: 8B alignment for b64 DS ops, 2-way bank
// aliasing only (free, m136).
#define ROWSTRIDE 68

// 2*log2(e): folded into Wf fragments + bias so the MFMA output is already
// the exp2 argument.  tanh(z) = 1 - 2/(exp2(2*log2e*z)+1).
#define TANH_SCALE 2.8853900817779268f
// clamp scaled arg at |2*log2e*z| <= 26.56  (|z| <= 9.2, where tanh==1.0f in f32).
// Also guarantees exp2 <= 9.9e7 so the 4-way product cannot overflow.
#define SCLAMP 26.56f

__device__ __forceinline__ f32x16 splat16(float c) {
    f32x16 v;
    #pragma unroll
    for (int i = 0; i < 16; ++i) v[i] = c;
    return v;
}

// tanh from pre-scaled argument s = 2*log2e*z, elementwise on a C-frag.
// Shared-reciprocal: one v_rcp serves 4 elements (trans: 1 exp2/elem + 0.25 rcp/elem).
__device__ __forceinline__ f32x16 tanh_from_scaled(f32x16 s) {
    f32x16 e;
    #pragma unroll
    for (int i = 0; i < 16; ++i)
        e[i] = __builtin_amdgcn_exp2f(__builtin_amdgcn_fmed3f(s[i], -SCLAMP, SCLAMP));
    f32x16 o;
    #pragma unroll
    for (int g = 0; g < 4; ++g) {
        float d0 = e[4*g+0] + 1.0f, d1 = e[4*g+1] + 1.0f;
        float d2 = e[4*g+2] + 1.0f, d3 = e[4*g+3] + 1.0f;
        float p01 = d0 * d1, p23 = d2 * d3;
        float r   = __builtin_amdgcn_rcpf(p01 * p23);
        float r01 = r * p23, r23 = r * p01;          // 1/p01, 1/p23
        o[4*g+0] = __builtin_fmaf(-2.0f, r01 * d1, 1.0f);   // 1 - 2/d0
        o[4*g+1] = __builtin_fmaf(-2.0f, r01 * d0, 1.0f);
        o[4*g+2] = __builtin_fmaf(-2.0f, r23 * d3, 1.0f);
        o[4*g+3] = __builtin_fmaf(-2.0f, r23 * d2, 1.0f);
    }
    return o;
}

__device__ __forceinline__ half2v pack_f16(float a, float b) {
    return __builtin_bit_cast(half2v, __builtin_amdgcn_cvt_pkrtz(a, b));
}

// State layout per wave (transposed): Y^T[dim=64][batch=32], two 32x32 MFMA
// C-frags: value (t, reg) at lane (h=lane>>5, b=lane&31):
//   dim = 32*t + (reg&3) + 8*(reg>>2) + 4*h,  batch = b
__global__ __launch_bounds__(256) void ode_rk4_kernel(
    const float* __restrict__ x,
    const float* __restrict__ W_in,  const float* __restrict__ b_in,
    const float* __restrict__ Wf,    const float* __restrict__ bf,
    const float* __restrict__ W_out, const float* __restrict__ b_out,
    float* __restrict__ out)
{
    __shared__ _Float16 lds[4 * 32 * ROWSTRIDE];

    const int tid  = threadIdx.x;
    const int wv   = tid >> 6;
    const int lane = tid & 63;
    const int b    = lane & 31;   // batch column owned by this lane
    const int h    = lane >> 5;   // half-wave index
    _Float16* rowp = &lds[(wv * 32 + b) * ROWSTRIDE];

    const int batch0 = (blockIdx.x * 4 + wv) * 32;

    // ---- constant fragments: A = TANH_SCALE * Wf^T (scale folded into weights) ----
    half8v a_wf0[4], a_wf1[4];
    #pragma unroll
    for (int q = 0; q < 4; ++q) {
        #pragma unroll
        for (int j = 0; j < 8; ++j) {
            int k = 16 * q + 8 * h + j;
            a_wf0[q][j] = (_Float16)(Wf[k * 64 + b]      * TANH_SCALE);
            a_wf1[q][j] = (_Float16)(Wf[k * 64 + 32 + b] * TANH_SCALE);
        }
    }
    // scaled bias in C-layout (MFMA C-init: free bias add)
    f32x16 bias0, bias1;
    #pragma unroll
    for (int r = 0; r < 16; ++r) {
        int row = (r & 3) + 8 * (r >> 2) + 4 * h;
        bias0[r] = bf[row]      * TANH_SCALE;
        bias1[r] = bf[32 + row] * TANH_SCALE;
    }

    // ---- input layer: Y0^T = W_in^T @ x^T + b_in (single K-tile, K=16) ----
    f32x16 y0v, y1v;
    {
        const float* xp = x + (batch0 + b) * IN_DIM + 8 * h;
        float4 xa = *(const float4*)xp;
        float4 xc = *(const float4*)(xp + 4);
        half2v q0 = pack_f16(xa.x, xa.y);
        half2v q1 = pack_f16(xa.z, xa.w);
        half2v q2 = pack_f16(xc.x, xc.y);
        half2v q3 = pack_f16(xc.z, xc.w);
        half4v lo = __builtin_shufflevector(q0, q1, 0, 1, 2, 3);
        half4v hi = __builtin_shufflevector(q2, q3, 0, 1, 2, 3);
        half8v bx = __builtin_shufflevector(lo, hi, 0, 1, 2, 3, 4, 5, 6, 7);

        half8v a0, a1;
        #pragma unroll
        for (int j = 0; j < 8; ++j) {
            int k = 8 * h + j;                 // k in [0,16)
            a0[j] = (_Float16)W_in[k * 64 + b];
            a1[j] = (_Float16)W_in[k * 64 + 32 + b];
        }
        f32x16 c0, c1;
        #pragma unroll
        for (int r = 0; r < 16; ++r) {
            int row = (r & 3) + 8 * (r >> 2) + 4 * h;
            c0[r] = b_in[row];
            c1[r] = b_in[32 + row];
        }
        y0v = __builtin_amdgcn_mfma_f32_32x32x16_f16(a0, bx, c0, 0, 0, 0);
        y1v = __builtin_amdgcn_mfma_f32_32x32x16_f16(a1, bx, c1, 0, 0, 0);
    }

    // Pack given values (already the f-eval argument) to f16 B-frags via
    // wave-private LDS round-trip.  Write: lane (h,b) owns dims {32t+8g+4h+i};
    // read: B[k=16q+8h+j][n=b].
    auto build_frags = [&](const f32x16& v0, const f32x16& v1, half8v* bb) {
        #pragma unroll
        for (int t = 0; t < 2; ++t) {
            const f32x16& vv = t ? v1 : v0;
            #pragma unroll
            for (int g = 0; g < 4; ++g) {
                half2v p0 = pack_f16(vv[4 * g + 0], vv[4 * g + 1]);
                half2v p1 = pack_f16(vv[4 * g + 2], vv[4 * g + 3]);
                half4v pk = __builtin_shufflevector(p0, p1, 0, 1, 2, 3);
                *(half4v*)(rowp + 32 * t + 8 * g + 4 * h) = pk;
            }
        }
        // wave-private scratch: in-order DS per wave + lgkmcnt(0) is sufficient
        __asm__ volatile("s_waitcnt lgkmcnt(0)" ::: "memory");
        #pragma unroll
        for (int q = 0; q < 4; ++q) {
            half4v lo = *(const half4v*)(rowp + 16 * q + 8 * h);
            half4v hi = *(const half4v*)(rowp + 16 * q + 8 * h + 4);
            bb[q] = __builtin_shufflevector(lo, hi, 0, 1, 2, 3, 4, 5, 6, 7);
        }
        // next iteration's DS writes must not hoist above these reads
        __asm__ volatile("" ::: "memory");
    };

    // k = tanh(Wf @ arg + bf), arg given as two C-frags
    auto feval = [&](const f32x16& a0, const f32x16& a1, f32x16& ko0, f32x16& ko1) {
        half8v bb[4];
        build_frags(a0, a1, bb);
        f32x16 s0 = bias0, s1 = bias1;
        #pragma unroll
        for (int q = 0; q < 4; ++q) {
            s0 = __builtin_amdgcn_mfma_f32_32x32x16_f16(a_wf0[q], bb[q], s0, 0, 0, 0);
            s1 = __builtin_amdgcn_mfma_f32_32x32x16_f16(a_wf1[q], bb[q], s1, 0, 0, 0);
        }
        ko0 = tanh_from_scaled(s0);
        ko1 = tanh_from_scaled(s1);
    };

    const float dt = 1.0f / N_STEPS;
    const f32x16 c16 = splat16(dt / 6.0f);
    const f32x16 c13 = splat16(dt / 3.0f);
    const f32x16 ch  = splat16(0.5f * dt);
    const f32x16 c1  = splat16(dt);

    #pragma unroll 1
    for (int s = 0; s < N_STEPS; ++s) {
        f32x16 k0, k1, yn0, yn1, t0, t1;

        feval(y0v, y1v, k0, k1);                    // k1 (arg = y, no fma)
        yn0 = y0v + c16 * k0;  yn1 = y1v + c16 * k1;
        t0  = y0v + ch  * k0;  t1  = y1v + ch  * k1;

        feval(t0, t1, k0, k1);                      // k2
        yn0 = yn0 + c13 * k0;  yn1 = yn1 + c13 * k1;
        t0  = y0v + ch  * k0;  t1  = y1v + ch  * k1;

        feval(t0, t1, k0, k1);                      // k3
        yn0 = yn0 + c13 * k0;  yn1 = yn1 + c13 * k1;
        t0  = y0v + c1  * k0;  t1  = y1v + c1  * k1;

        feval(t0, t1, k0, k1);                      // k4
        y0v = yn0 + c16 * k0;  y1v = yn1 + c16 * k1;
    }

    // ---- readout: out^T = W_out^T @ y1^T + b_out ----
    {
        half8v bb[4];
        build_frags(y0v, y1v, bb);
        half8v a_wo[4];
        #pragma unroll
        for (int q = 0; q < 4; ++q) {
            #pragma unroll
            for (int j = 0; j < 8; ++j) {
                int k = 16 * q + 8 * h + j;
                a_wo[q][j] = (b < OUT_DIM) ? (_Float16)W_out[k * OUT_DIM + b]
                                           : (_Float16)0.0f;
            }
        }
        f32x16 so;
        #pragma unroll
        for (int r = 0; r < 16; ++r) {
            int o = (r & 3) + 8 * (r >> 2) + 4 * h;
            so[r] = (r < 8) ? b_out[o] : 0.0f;
        }
        #pragma unroll
        for (int q = 0; q < 4; ++q)
            so = __builtin_amdgcn_mfma_f32_32x32x16_f16(a_wo[q], bb[q], so, 0, 0, 0);

        // lane (h,b): regs 0-3 -> out dims 4h+0..3, regs 4-7 -> 8+4h+0..3
        float* op = out + (batch0 + b) * OUT_DIM;
        float4 o0 = make_float4(so[0], so[1], so[2], so[3]);
        float4 o1 = make_float4(so[4], so[5], so[6], so[7]);
        *(float4*)(op + 4 * h)     = o0;
        *(float4*)(op + 8 + 4 * h) = o1;
    }
}

extern "C" void kernel_launch(void* const* d_in, const int* in_sizes, int n_in,
                              void* d_out, int out_size, void* d_ws, size_t ws_size,
                              hipStream_t stream) {
    const float* x     = (const float*)d_in[0];
    const float* W_in  = (const float*)d_in[1];
    const float* b_in  = (const float*)d_in[2];
    const float* Wf    = (const float*)d_in[3];
    const float* bf    = (const float*)d_in[4];
    const float* W_out = (const float*)d_in[5];
    const float* b_out = (const float*)d_in[6];
    float* outp        = (float*)d_out;

    dim3 grid(BATCH / 128);   // 4 waves/block, 32 batch rows per wave
    dim3 block(256);
    hipLaunchKernelGGL(ode_rk4_kernel, grid, block, 0, stream,
                       x, W_in, b_in, Wf, bf, W_out, b_out, outp);
}

// Round 4
// 2514.373 us; speedup vs baseline: 1.0837x; 1.0837x over previous
//
#include <hip/hip_runtime.h>

#define BATCH    1048576
#define IN_DIM   16
#define ODE_DIM  64
#define OUT_DIM  16
#define N_STEPS  32

typedef _Float16 half2v __attribute__((ext_vector_type(2)));
typedef _Float16 half4v __attribute__((ext_vector_type(4)));
typedef _Float16 half8v __attribute__((ext_vector_type(8)));
typedef float    f32x16 __attribute__((ext_vector_type(16)));

// 64 dims + 4 pad halfs per row: 8B alignment for b64 DS ops, benign aliasing.
#define ROWSTRIDE 68

// 2*log2(e), folded into Wf fragments + bias: MFMA output is the exp2 arg.
// tanh(z) = 1 - 2/(exp2(2*log2e*z)+1).
#define TANH_SCALE 2.8853900817779268f
// clamp so the 4-way product in the shared-rcp cannot overflow; tanh==1.0f beyond.
#define SCLAMP 26.56f

__device__ __forceinline__ half2v pack_f16(float a, float b) {
    return __builtin_bit_cast(half2v, __builtin_amdgcn_cvt_pkrtz(a, b));
}

// tanh from pre-scaled arg s = 2*log2e*z, on a 16-elem C-frag.
// Shared reciprocal: one v_rcp per 4 elems.
__device__ __forceinline__ f32x16 tanh_from_scaled(f32x16 s) {
    f32x16 e;
    #pragma unroll
    for (int i = 0; i < 16; ++i)
        e[i] = __builtin_amdgcn_exp2f(__builtin_amdgcn_fmed3f(s[i], -SCLAMP, SCLAMP));
    f32x16 o;
    #pragma unroll
    for (int g = 0; g < 4; ++g) {
        float d0 = e[4*g+0] + 1.0f, d1 = e[4*g+1] + 1.0f;
        float d2 = e[4*g+2] + 1.0f, d3 = e[4*g+3] + 1.0f;
        float p01 = d0 * d1, p23 = d2 * d3;
        float r   = __builtin_amdgcn_rcpf(p01 * p23);
        float r01 = r * p23, r23 = r * p01;
        o[4*g+0] = __builtin_fmaf(-2.0f, r01 * d1, 1.0f);
        o[4*g+1] = __builtin_fmaf(-2.0f, r01 * d0, 1.0f);
        o[4*g+2] = __builtin_fmaf(-2.0f, r23 * d3, 1.0f);
        o[4*g+3] = __builtin_fmaf(-2.0f, r23 * d2, 1.0f);
    }
    return o;
}

// M-SPLIT layout: a PAIR of waves shares 32 batch elements; wave w of the pair
// owns dims [32w, 32w+32).  Per-wave state is ONE 32x32 C-frag (16 f32 regs):
//   value (reg r) at lane (h=lane>>5, b=lane&31):
//     dim_local = (r&3) + 8*(r>>2) + 4*h   (global dim = 32w + dim_local)
//     batch     = b
// f-eval: each wave computes k for its dim-half; halves are exchanged through
// a double-buffered LDS row region (one __syncthreads per f-eval), then each
// wave runs 4 MFMAs (its M-tile x full K=64) with A = TANH_SCALE*Wf^T constant
// in registers.  Register budget ~150 -> 3 waves/SIMD (vs 2 before).
__global__ __launch_bounds__(256, 3) void ode_rk4_kernel(
    const float* __restrict__ x,
    const float* __restrict__ W_in,  const float* __restrict__ b_in,
    const float* __restrict__ Wf,    const float* __restrict__ bf,
    const float* __restrict__ W_out, const float* __restrict__ b_out,
    float* __restrict__ out)
{
    __shared__ _Float16 lds[2][2][32][ROWSTRIDE];  // [buf][pair][row=batch][dim halfs]

    const int tid  = threadIdx.x;
    const int wv   = tid >> 6;
    const int pair = wv >> 1;
    const int w    = wv & 1;      // M-tile: dims [32w, 32w+32)
    const int lane = tid & 63;
    const int b    = lane & 31;   // batch column owned by this lane
    const int h    = lane >> 5;

    const int batch0 = blockIdx.x * 64 + pair * 32;

    // ---- constant A-frags for own M-tile: A[m][k] = SCALE*Wf[k][32w+m] ----
    half8v a_wf[4];
    #pragma unroll
    for (int q = 0; q < 4; ++q) {
        #pragma unroll
        for (int j = 0; j < 8; ++j) {
            int k = 16 * q + 8 * h + j;
            a_wf[q][j] = (_Float16)(Wf[k * 64 + 32 * w + b] * TANH_SCALE);
        }
    }
    // scaled bias, C-layout (free bias add as MFMA C-init)
    f32x16 bias;
    #pragma unroll
    for (int r = 0; r < 16; ++r) {
        int row = (r & 3) + 8 * (r >> 2) + 4 * h;
        bias[r] = bf[32 * w + row] * TANH_SCALE;
    }

    // ---- input layer: y_half = W_in^T @ x^T + b_in  (K=16, one MFMA) ----
    f32x16 y;
    {
        const float* xp = x + (batch0 + b) * IN_DIM + 8 * h;
        float4 xa = *(const float4*)xp;
        float4 xc = *(const float4*)(xp + 4);
        half2v q0 = pack_f16(xa.x, xa.y);
        half2v q1 = pack_f16(xa.z, xa.w);
        half2v q2 = pack_f16(xc.x, xc.y);
        half2v q3 = pack_f16(xc.z, xc.w);
        half4v lo = __builtin_shufflevector(q0, q1, 0, 1, 2, 3);
        half4v hi = __builtin_shufflevector(q2, q3, 0, 1, 2, 3);
        half8v bx = __builtin_shufflevector(lo, hi, 0, 1, 2, 3, 4, 5, 6, 7);

        half8v a_in;
        #pragma unroll
        for (int j = 0; j < 8; ++j)
            a_in[j] = (_Float16)W_in[(8 * h + j) * 64 + 32 * w + b];
        f32x16 c0;
        #pragma unroll
        for (int r = 0; r < 16; ++r) {
            int row = (r & 3) + 8 * (r >> 2) + 4 * h;
            c0[r] = b_in[32 * w + row];
        }
        y = __builtin_amdgcn_mfma_f32_32x32x16_f16(a_in, bx, c0, 0, 0, 0);
    }

    // Exchange own dim-half (f32 C-frag -> f16), barrier, read full-K B-frags.
    // Double-buffered: exactly one __syncthreads per exchange is hazard-free
    // (re-write of a buffer is always separated by the next exchange's barrier).
    int bufi = 0;
    auto exchange = [&](const f32x16& v, half8v* bb) {
        _Float16* rowp = &lds[bufi][pair][b][0];
        #pragma unroll
        for (int g = 0; g < 4; ++g) {
            half2v p0 = pack_f16(v[4 * g + 0], v[4 * g + 1]);
            half2v p1 = pack_f16(v[4 * g + 2], v[4 * g + 3]);
            half4v pk = __builtin_shufflevector(p0, p1, 0, 1, 2, 3);
            *(half4v*)(rowp + 32 * w + 8 * g + 4 * h) = pk;
        }
        __syncthreads();
        #pragma unroll
        for (int q = 0; q < 4; ++q) {
            half4v lo = *(const half4v*)(rowp + 16 * q + 8 * h);
            half4v hi = *(const half4v*)(rowp + 16 * q + 8 * h + 4);
            bb[q] = __builtin_shufflevector(lo, hi, 0, 1, 2, 3, 4, 5, 6, 7);
        }
        bufi ^= 1;
    };

    // k_half = tanh(S*(Wf @ arg + bf)) for own M-tile; arg passed as C-frag half
    auto feval = [&](const f32x16& arg, f32x16& ko) {
        half8v bb[4];
        exchange(arg, bb);
        f32x16 s = bias;
        #pragma unroll
        for (int q = 0; q < 4; ++q)
            s = __builtin_amdgcn_mfma_f32_32x32x16_f16(a_wf[q], bb[q], s, 0, 0, 0);
        ko = tanh_from_scaled(s);
    };

    const float dt  = 1.0f / N_STEPS;
    const float c16 = dt / 6.0f, c13 = dt / 3.0f, ch = 0.5f * dt;

    #pragma unroll 1
    for (int st = 0; st < N_STEPS; ++st) {
        f32x16 k, yn, t;

        feval(y, k);                                   // k1
        #pragma unroll
        for (int r = 0; r < 16; ++r) {
            yn[r] = __builtin_fmaf(c16, k[r], y[r]);
            t[r]  = __builtin_fmaf(ch,  k[r], y[r]);
        }
        feval(t, k);                                   // k2
        #pragma unroll
        for (int r = 0; r < 16; ++r) {
            yn[r] = __builtin_fmaf(c13, k[r], yn[r]);
            t[r]  = __builtin_fmaf(ch,  k[r], y[r]);
        }
        feval(t, k);                                   // k3
        #pragma unroll
        for (int r = 0; r < 16; ++r) {
            yn[r] = __builtin_fmaf(c13, k[r], yn[r]);
            t[r]  = __builtin_fmaf(dt,  k[r], y[r]);
        }
        feval(t, k);                                   // k4
        #pragma unroll
        for (int r = 0; r < 16; ++r)
            y[r] = __builtin_fmaf(c16, k[r], yn[r]);
    }

    // ---- readout: exchange y, then wave w==0 of each pair does W_out MFMA ----
    {
        half8v bb[4];
        exchange(y, bb);
        if (w == 0) {
            half8v a_wo[4];
            #pragma unroll
            for (int q = 0; q < 4; ++q) {
                #pragma unroll
                for (int j = 0; j < 8; ++j) {
                    int k = 16 * q + 8 * h + j;
                    a_wo[q][j] = (b < OUT_DIM) ? (_Float16)W_out[k * OUT_DIM + b]
                                               : (_Float16)0.0f;
                }
            }
            f32x16 so;
            #pragma unroll
            for (int r = 0; r < 16; ++r) {
                int o = (r & 3) + 8 * (r >> 2) + 4 * h;
                so[r] = (r < 8) ? b_out[o] : 0.0f;
            }
            #pragma unroll
            for (int q = 0; q < 4; ++q)
                so = __builtin_amdgcn_mfma_f32_32x32x16_f16(a_wo[q], bb[q], so, 0, 0, 0);

            float* op = out + (batch0 + b) * OUT_DIM;
            *(float4*)(op + 4 * h)     = make_float4(so[0], so[1], so[2], so[3]);
            *(float4*)(op + 8 + 4 * h) = make_float4(so[4], so[5], so[6], so[7]);
        }
    }
}

extern "C" void kernel_launch(void* const* d_in, const int* in_sizes, int n_in,
                              void* d_out, int out_size, void* d_ws, size_t ws_size,
                              hipStream_t stream) {
    const float* x     = (const float*)d_in[0];
    const float* W_in  = (const float*)d_in[1];
    const float* b_in  = (const float*)d_in[2];
    const float* Wf    = (const float*)d_in[3];
    const float* bf    = (const float*)d_in[4];
    const float* W_out = (const float*)d_in[5];
    const float* b_out = (const float*)d_in[6];
    float* outp        = (float*)d_out;

    dim3 grid(BATCH / 64);    // 4 waves = 2 pairs per block, 32 batch per pair
    dim3 block(256);
    hipLaunchKernelGGL(ode_rk4_kernel, grid, block, 0, stream,
                       x, W_in, b_in, Wf, bf, W_out, b_out, outp);
}

// Round 5
// 2145.868 us; speedup vs baseline: 1.2698x; 1.1717x over previous
//
#include <hip/hip_runtime.h>

#define BATCH    1048576
#define IN_DIM   16
#define ODE_DIM  64
#define OUT_DIM  16
#define N_STEPS  32

typedef _Float16 half2v __attribute__((ext_vector_type(2)));
typedef _Float16 half8v __attribute__((ext_vector_type(8)));
typedef float    f32x16 __attribute__((ext_vector_type(16)));
typedef unsigned u32x2  __attribute__((ext_vector_type(2)));
typedef unsigned u32x4  __attribute__((ext_vector_type(4)));

// 2*log2(e), folded into Wf fragments + bias: the MFMA output is already the
// exp2 argument.  tanh(z) = 1 - 2/(exp2(2*log2e*z)+1); robust at +/-inf.
#define TANH_SCALE 2.8853900817779268f

__device__ __forceinline__ unsigned pack_f16u(float a, float b) {
    return __builtin_bit_cast(unsigned, __builtin_amdgcn_cvt_pkrtz(a, b));
}

// Exchange: A' = {A.lo32, B.lo32}, B' = {A.hi32, B.hi32}  (lane halves).
// v_permlane32_swap_b32 swaps lanes[32:63] of first operand with lanes[0:31]
// of second; returns (new_first, new_second) = exactly (A', B').
__device__ __forceinline__ void xchg32(unsigned& A, unsigned& B, int lane) {
#if __has_builtin(__builtin_amdgcn_permlane32_swap)
    u32x2 r = __builtin_amdgcn_permlane32_swap(A, B, false, false);
    A = r[0];
    B = r[1];
#else
    unsigned Ax = (unsigned)__shfl_xor((int)A, 32, 64);
    unsigned Bx = (unsigned)__shfl_xor((int)B, 32, 64);
    bool lo = lane < 32;
    unsigned X = lo ? A : Bx;
    unsigned Y = lo ? Ax : B;
    A = X;
    B = Y;
#endif
}

// Fully wave-private kernel: each wave owns 32 batch x all 64 dims.
// State in two 32x32 MFMA C-frags (f32x16): value (t, reg r) at lane (h,b):
//   dim = 32t + (r&3) + 8*(r>>2) + 4h,  batch = b   (b=lane&31, h=lane>>5)
// Per f-eval: t-arg packed to f16 pairs (pkrtz), C->B layout transform done
// IN-REGISTER with 8 v_permlane32_swap (no LDS, no barriers), 8 MFMAs with
// A = TANH_SCALE*Wf^T constant in registers, then elementwise tanh.
__global__ __launch_bounds__(256, 2) void ode_rk4_kernel(
    const float* __restrict__ x,
    const float* __restrict__ W_in,  const float* __restrict__ b_in,
    const float* __restrict__ Wf,    const float* __restrict__ bf,
    const float* __restrict__ W_out, const float* __restrict__ b_out,
    float* __restrict__ out)
{
    const int tid  = threadIdx.x;
    const int wv   = tid >> 6;
    const int lane = tid & 63;
    const int b    = lane & 31;
    const int h    = lane >> 5;

    const int batch0 = (blockIdx.x * 4 + wv) * 32;

    // ---- constant A-frags: A[m][k] = TANH_SCALE * Wf[k][m], two M-tiles ----
    half8v a_wf0[4], a_wf1[4];
    #pragma unroll
    for (int q = 0; q < 4; ++q) {
        #pragma unroll
        for (int j = 0; j < 8; ++j) {
            int k = 16 * q + 8 * h + j;
            a_wf0[q][j] = (_Float16)(Wf[k * 64 + b]      * TANH_SCALE);
            a_wf1[q][j] = (_Float16)(Wf[k * 64 + 32 + b] * TANH_SCALE);
        }
    }
    // scaled bias in C-layout (free bias add as MFMA C-init)
    f32x16 bias0, bias1;
    #pragma unroll
    for (int r = 0; r < 16; ++r) {
        int row = (r & 3) + 8 * (r >> 2) + 4 * h;
        bias0[r] = bf[row]      * TANH_SCALE;
        bias1[r] = bf[32 + row] * TANH_SCALE;
    }

    // ---- input layer: Y0^T = W_in^T @ x^T + b_in (K=16, one MFMA pair) ----
    f32x16 y0v, y1v;
    {
        const float* xp = x + (batch0 + b) * IN_DIM + 8 * h;
        float4 xa = *(const float4*)xp;
        float4 xc = *(const float4*)(xp + 4);
        u32x4 bw;
        bw[0] = pack_f16u(xa.x, xa.y);
        bw[1] = pack_f16u(xa.z, xa.w);
        bw[2] = pack_f16u(xc.x, xc.y);
        bw[3] = pack_f16u(xc.z, xc.w);
        half8v bx = __builtin_bit_cast(half8v, bw);

        half8v a0, a1;
        #pragma unroll
        for (int j = 0; j < 8; ++j) {
            int k = 8 * h + j;
            a0[j] = (_Float16)W_in[k * 64 + b];
            a1[j] = (_Float16)W_in[k * 64 + 32 + b];
        }
        f32x16 c0, c1;
        #pragma unroll
        for (int r = 0; r < 16; ++r) {
            int row = (r & 3) + 8 * (r >> 2) + 4 * h;
            c0[r] = b_in[row];
            c1[r] = b_in[32 + row];
        }
        y0v = __builtin_amdgcn_mfma_f32_32x32x16_f16(a0, bx, c0, 0, 0, 0);
        y1v = __builtin_amdgcn_mfma_f32_32x32x16_f16(a1, bx, c1, 0, 0, 0);
    }

    // Pack arg = y + c*k (C-layout) into f16 and transform C->B in-register.
    // pk[t][l] = pkrtz(arg[2l], arg[2l+1]);  after swapping pairs
    // (0,2),(1,3),(4,6),(5,7) per t, frag q (k=16q..16q+15) is words
    // pk[q>>1][4*(q&1) .. +3].
    auto build_frags = [&](float c, const f32x16& k0, const f32x16& k1,
                           half8v* bb) {
        unsigned pk[2][8];
        #pragma unroll
        for (int t = 0; t < 2; ++t) {
            const f32x16& yy = t ? y1v : y0v;
            const f32x16& kv = t ? k1 : k0;
            #pragma unroll
            for (int l = 0; l < 8; ++l) {
                float a, bv;
                if (c != 0.0f) {
                    a  = __builtin_fmaf(c, kv[2 * l],     yy[2 * l]);
                    bv = __builtin_fmaf(c, kv[2 * l + 1], yy[2 * l + 1]);
                } else {
                    a  = yy[2 * l];
                    bv = yy[2 * l + 1];
                }
                pk[t][l] = pack_f16u(a, bv);
            }
        }
        #pragma unroll
        for (int t = 0; t < 2; ++t) {
            xchg32(pk[t][0], pk[t][2], lane);
            xchg32(pk[t][1], pk[t][3], lane);
            xchg32(pk[t][4], pk[t][6], lane);
            xchg32(pk[t][5], pk[t][7], lane);
        }
        #pragma unroll
        for (int q = 0; q < 4; ++q) {
            u32x4 w;
            w[0] = pk[q >> 1][4 * (q & 1) + 0];
            w[1] = pk[q >> 1][4 * (q & 1) + 1];
            w[2] = pk[q >> 1][4 * (q & 1) + 2];
            w[3] = pk[q >> 1][4 * (q & 1) + 3];
            bb[q] = __builtin_bit_cast(half8v, w);
        }
    };

    // k = tanh(S*(Wf @ (y + c*kin) + bf)); simple 2-trans tanh (robust at inf)
    auto feval = [&](float c, const f32x16& ki0, const f32x16& ki1,
                     f32x16& ko0, f32x16& ko1) {
        half8v bb[4];
        build_frags(c, ki0, ki1, bb);
        f32x16 s0 = bias0, s1 = bias1;
        #pragma unroll
        for (int q = 0; q < 4; ++q) {
            s0 = __builtin_amdgcn_mfma_f32_32x32x16_f16(a_wf0[q], bb[q], s0, 0, 0, 0);
            s1 = __builtin_amdgcn_mfma_f32_32x32x16_f16(a_wf1[q], bb[q], s1, 0, 0, 0);
        }
        #pragma unroll
        for (int r = 0; r < 16; ++r) {
            float e0 = __builtin_amdgcn_exp2f(s0[r]);
            float e1 = __builtin_amdgcn_exp2f(s1[r]);
            ko0[r] = __builtin_fmaf(-2.0f, __builtin_amdgcn_rcpf(e0 + 1.0f), 1.0f);
            ko1[r] = __builtin_fmaf(-2.0f, __builtin_amdgcn_rcpf(e1 + 1.0f), 1.0f);
        }
    };

    const float dt  = 1.0f / N_STEPS;
    const float ch  = 0.5f * dt, c16 = dt / 6.0f;

    #pragma unroll 1
    for (int st = 0; st < N_STEPS; ++st) {
        f32x16 k0, k1, ks0, ks1;

        feval(0.0f, y0v, y1v, k0, k1);           // k1 (arg = y)
        ks0 = k0;  ks1 = k1;
        feval(ch, k0, k1, k0, k1);               // k2 (arg = y + dt/2 k1)
        #pragma unroll
        for (int r = 0; r < 16; ++r) {
            ks0[r] = __builtin_fmaf(2.0f, k0[r], ks0[r]);
            ks1[r] = __builtin_fmaf(2.0f, k1[r], ks1[r]);
        }
        feval(ch, k0, k1, k0, k1);               // k3
        #pragma unroll
        for (int r = 0; r < 16; ++r) {
            ks0[r] = __builtin_fmaf(2.0f, k0[r], ks0[r]);
            ks1[r] = __builtin_fmaf(2.0f, k1[r], ks1[r]);
        }
        feval(dt, k0, k1, k0, k1);               // k4
        #pragma unroll
        for (int r = 0; r < 16; ++r) {
            ks0[r] += k0[r];
            ks1[r] += k1[r];
            y0v[r] = __builtin_fmaf(c16, ks0[r], y0v[r]);
            y1v[r] = __builtin_fmaf(c16, ks1[r], y1v[r]);
        }
    }

    // ---- readout: out^T = W_out^T @ y1^T + b_out ----
    {
        half8v bb[4];
        build_frags(0.0f, y0v, y1v, bb);
        half8v a_wo[4];
        #pragma unroll
        for (int q = 0; q < 4; ++q) {
            #pragma unroll
            for (int j = 0; j < 8; ++j) {
                int k = 16 * q + 8 * h + j;
                a_wo[q][j] = (b < OUT_DIM) ? (_Float16)W_out[k * OUT_DIM + b]
                                           : (_Float16)0.0f;
            }
        }
        f32x16 so;
        #pragma unroll
        for (int r = 0; r < 16; ++r) {
            int o = (r & 3) + 8 * (r >> 2) + 4 * h;
            so[r] = (r < 8) ? b_out[o] : 0.0f;
        }
        #pragma unroll
        for (int q = 0; q < 4; ++q)
            so = __builtin_amdgcn_mfma_f32_32x32x16_f16(a_wo[q], bb[q], so, 0, 0, 0);

        // lane (h,b): regs 0-3 -> out dims 4h+0..3, regs 4-7 -> 8+4h+0..3
        float* op = out + (batch0 + b) * OUT_DIM;
        *(float4*)(op + 4 * h)     = make_float4(so[0], so[1], so[2], so[3]);
        *(float4*)(op + 8 + 4 * h) = make_float4(so[4], so[5], so[6], so[7]);
    }
}

extern "C" void kernel_launch(void* const* d_in, const int* in_sizes, int n_in,
                              void* d_out, int out_size, void* d_ws, size_t ws_size,
                              hipStream_t stream) {
    const float* x     = (const float*)d_in[0];
    const float* W_in  = (const float*)d_in[1];
    const float* b_in  = (const float*)d_in[2];
    const float* Wf    = (const float*)d_in[3];
    const float* bf    = (const float*)d_in[4];
    const float* W_out = (const float*)d_in[5];
    const float* b_out = (const float*)d_in[6];
    float* outp        = (float*)d_out;

    dim3 grid(BATCH / 128);   // 4 waves/block, 32 batch per wave, no LDS
    dim3 block(256);
    hipLaunchKernelGGL(ode_rk4_kernel, grid, block, 0, stream,
                       x, W_in, b_in, Wf, bf, W_out, b_out, outp);
}